// Round 2
// baseline (2360.638 us; speedup 1.0000x reference)
//
#include <hip/hip_runtime.h>
#include <hip/hip_bf16.h>
#include <math.h>

#define BATCH 8
#define LRAW 131072
#define L1P 32768
#define L2P 8192
#define SEQ 2048
#define DMODEL 256
#define NHEAD 8
#define DHEAD 32
#define MDIM 128
#define MHALF 64
#define DFF 1024
#define BS_TOK (BATCH*SEQ)          /* 16384 tokens */
#define INV_SQRT_M 0.08838834764831845f  /* 1/sqrt(128) */

// ---------------- conv stem ----------------

__global__ __launch_bounds__(256) void conv0_kernel(const float* __restrict__ x,
    const float* __restrict__ w, const float* __restrict__ bias, float* __restrict__ out)
{
    int idx = blockIdx.x * 256 + threadIdx.x;           // over B*L1P
    if (idx >= BATCH * L1P) return;
    int b = idx >> 15;
    int p = idx & (L1P - 1);
    const float* xb = x + (size_t)b * LRAW;
    float acc[8];
#pragma unroll
    for (int c = 0; c < 8; c++) acc[c] = 0.f;
#pragma unroll
    for (int i = 0; i < 4; i++) {
        int base = 4 * p + i - 5;                        // K=11, pad 5/5
        float y[8];
#pragma unroll
        for (int c = 0; c < 8; c++) y[c] = bias[c];
#pragma unroll
        for (int kk = 0; kk < 11; kk++) {
            int xi = base + kk;
            float xv = (xi >= 0 && xi < LRAW) ? xb[xi] : 0.f;
#pragma unroll
            for (int c = 0; c < 8; c++) y[c] = fmaf(xv, w[kk * 8 + c], y[c]);
        }
#pragma unroll
        for (int c = 0; c < 8; c++) acc[c] += fmaxf(y[c], 0.f);
    }
    float* op = out + (size_t)idx * 8;
#pragma unroll
    for (int c = 0; c < 8; c++) op[c] = acc[c] * 0.25f;
}

__global__ __launch_bounds__(256) void conv1_kernel(const float* __restrict__ in,
    const float* __restrict__ w, const float* __restrict__ bias, float* __restrict__ out)
{
    int idx = blockIdx.x * 256 + threadIdx.x;           // over B*L2P
    if (idx >= BATCH * L2P) return;
    int b = idx >> 13;
    int p = idx & (L2P - 1);
    const float* ib = in + (size_t)b * L1P * 8;
    float acc[16];
#pragma unroll
    for (int c = 0; c < 16; c++) acc[c] = 0.f;
#pragma unroll
    for (int i = 0; i < 4; i++) {
        float y[16];
#pragma unroll
        for (int c = 0; c < 16; c++) y[c] = bias[c];
#pragma unroll
        for (int kk = 0; kk < 3; kk++) {
            int pos = 4 * p + i + kk - 1;               // K=3, pad 1/1
            if (pos < 0 || pos >= L1P) continue;
            const float* row = ib + (size_t)pos * 8;
#pragma unroll
            for (int ci = 0; ci < 8; ci++) {
                float xv = row[ci];
#pragma unroll
                for (int c = 0; c < 16; c++) y[c] = fmaf(xv, w[(kk * 8 + ci) * 16 + c], y[c]);
            }
        }
#pragma unroll
        for (int c = 0; c < 16; c++) acc[c] += fmaxf(y[c], 0.f);
    }
    float* op = out + (size_t)idx * 16;
#pragma unroll
    for (int c = 0; c < 16; c++) op[c] = acc[c] * 0.25f;
}

// one block per (b, p); 256 threads = one per output channel
__global__ __launch_bounds__(256) void conv2_kernel(const float* __restrict__ in,
    const float* __restrict__ w, const float* __restrict__ bias, float* __restrict__ out)
{
    int bp = blockIdx.x;
    int b = bp / SEQ, p = bp % SEQ;
    int co = threadIdx.x;
    __shared__ float win[6][16];
    int t = threadIdx.x;
    if (t < 96) {
        int r = t / 16, ci = t % 16;
        int pos = 4 * p - 1 + r;
        win[r][ci] = (pos >= 0 && pos < L2P) ? in[((size_t)b * L2P + pos) * 16 + ci] : 0.f;
    }
    __syncthreads();
    float y[4];
#pragma unroll
    for (int i = 0; i < 4; i++) y[i] = bias[co];
#pragma unroll
    for (int kk = 0; kk < 3; kk++) {
#pragma unroll
        for (int ci = 0; ci < 16; ci++) {
            float wv = w[(kk * 16 + ci) * 256 + co];
#pragma unroll
            for (int i = 0; i < 4; i++) y[i] = fmaf(win[i + kk][ci], wv, y[i]);
        }
    }
    float acc = 0.f;
#pragma unroll
    for (int i = 0; i < 4; i++) acc += fmaxf(y[i], 0.f);
    out[((size_t)b * SEQ + p) * 256 + co] = acc * 0.25f;
}

// ---------------- row mean (LayerCentering helper) ----------------
__global__ __launch_bounds__(64) void rowmean_kernel(const float* __restrict__ in, float* __restrict__ mean)
{
    int row = blockIdx.x;
    int l = threadIdx.x;
    const float* r = in + (size_t)row * DMODEL;
    float s = r[l] + r[l + 64] + r[l + 128] + r[l + 192];
#pragma unroll
    for (int off = 32; off > 0; off >>= 1) s += __shfl_down(s, off);
    if (l == 0) mean[row] = s * (1.0f / 256.0f);
}

// ---------------- f32 tiled GEMM (used for Wo): C = A @ W + bias [+resid] ----------------
template<bool SUB_MEAN, bool RELU, bool RESID>
__global__ __launch_bounds__(256) void gemm_kernel(const float* __restrict__ A,
    const float* __restrict__ W, const float* __restrict__ bias,
    const float* __restrict__ mean, const float* __restrict__ resid,
    float* __restrict__ C, int M, int N, int K)
{
    const int BM = 64, BN = 64, BK = 16;
    __shared__ float As[BK][BM];
    __shared__ float Bs[BK][BN];
    int tid = threadIdx.x;
    int n0 = blockIdx.x * BN, m0 = blockIdx.y * BM;
    int tx = tid & 15, ty = tid >> 4;
    int am = (tid * 4) / BK;
    int ak = (tid * 4) % BK;
    int bk = (tid * 4) / BN;
    int bn = (tid * 4) % BN;
    float sub = 0.f;
    if (SUB_MEAN) sub = mean[m0 + am];
    float acc[4][4] = {};
    for (int k0 = 0; k0 < K; k0 += BK) {
        float4 av = *(const float4*)(A + (size_t)(m0 + am) * K + k0 + ak);
        float4 wv = *(const float4*)(W + (size_t)(k0 + bk) * N + n0 + bn);
        As[ak + 0][am] = av.x - sub;
        As[ak + 1][am] = av.y - sub;
        As[ak + 2][am] = av.z - sub;
        As[ak + 3][am] = av.w - sub;
        *(float4*)(&Bs[bk][bn]) = wv;
        __syncthreads();
#pragma unroll
        for (int kk = 0; kk < BK; kk++) {
            float a[4], b[4];
#pragma unroll
            for (int i = 0; i < 4; i++) a[i] = As[kk][ty * 4 + i];
#pragma unroll
            for (int j = 0; j < 4; j++) b[j] = Bs[kk][tx * 4 + j];
#pragma unroll
            for (int i = 0; i < 4; i++)
#pragma unroll
                for (int j = 0; j < 4; j++) acc[i][j] = fmaf(a[i], b[j], acc[i][j]);
        }
        __syncthreads();
    }
#pragma unroll
    for (int i = 0; i < 4; i++) {
        int row = m0 + ty * 4 + i;
#pragma unroll
        for (int j = 0; j < 4; j++) {
            int col = n0 + tx * 4 + j;
            float val = acc[i][j] + bias[col];
            if (RESID) val += resid[(size_t)row * N + col];
            if (RELU) val = fmaxf(val, 0.f);
            C[(size_t)row * N + col] = val;
        }
    }
}

// ---------------- fused K/V projection + fourier + kv partial accumulation ----------------
// block per (b, h, sc); sc = quarter of the sequence (512 tokens)
__global__ __launch_bounds__(256) void phi_kv_fused(
    const float* __restrict__ hc, const float* __restrict__ mean,
    const float* __restrict__ Wk_l, const float* __restrict__ bk_l,
    const float* __restrict__ Wv_l, const float* __restrict__ bv_l,
    const float* __restrict__ om_l, const float* __restrict__ g_l,
    float* __restrict__ kvpart)
{
    int bx = blockIdx.x;
    int sc = bx & 3;
    int h = (bx >> 2) & 7;
    int b = bx >> 5;
    int tid = threadIdx.x;
    __shared__ float WkS[256][32];
    __shared__ float WvS[256][32];
    __shared__ float omS[32][64];
    __shared__ float hcS[8][256];
    __shared__ float kS[8][32];
    __shared__ float vS[8][32];
    __shared__ float ktS[8][128];
    {
        const float* wkp = Wk_l + (size_t)tid * 256 + h * 32;
        const float* wvp = Wv_l + (size_t)tid * 256 + h * 32;
#pragma unroll
        for (int e4 = 0; e4 < 32; e4 += 4) {
            *(float4*)&WkS[tid][e4] = *(const float4*)(wkp + e4);
            *(float4*)&WvS[tid][e4] = *(const float4*)(wvp + e4);
        }
    }
    for (int i = tid; i < 2048; i += 256) omS[i >> 6][i & 63] = om_l[(size_t)h * 2048 + i];
    float g = g_l[h];
    int e = tid & 31;
    int tsx = tid >> 5;
    float bke = bk_l[h * 32 + e];
    float bve = bv_l[h * 32 + e];
    int mb = tsx << 4;
    float accv[16] = {};
    int s_base = sc * 512;
    for (int s0 = 0; s0 < 512; s0 += 8) {
        __syncthreads();
        {   // load centered hc tile [8 tokens x 256]
            int row = b * SEQ + s_base + s0 + tsx;
            float mu = mean[row];
            int dc = e * 8;
            const float* hp = hc + (size_t)row * 256 + dc;
            float4 a0 = *(const float4*)hp;
            float4 a1 = *(const float4*)(hp + 4);
            hcS[tsx][dc + 0] = a0.x - mu; hcS[tsx][dc + 1] = a0.y - mu;
            hcS[tsx][dc + 2] = a0.z - mu; hcS[tsx][dc + 3] = a0.w - mu;
            hcS[tsx][dc + 4] = a1.x - mu; hcS[tsx][dc + 5] = a1.y - mu;
            hcS[tsx][dc + 6] = a1.z - mu; hcS[tsx][dc + 7] = a1.w - mu;
        }
        __syncthreads();
        {   // k,v projection: thread (token tsx, channel e)
            float ka = bke, va = bve;
            for (int d = 0; d < 256; d++) {
                float hv = hcS[tsx][d];
                ka = fmaf(hv, WkS[d][e], ka);
                va = fmaf(hv, WvS[d][e], va);
            }
            kS[tsx][e] = ka;
            vS[tsx][e] = va;
        }
        __syncthreads();
        {   // fourier features + exponential modulation (negative sign for k)
            int id = tid * 2;
            int t2 = id >> 6;
            int mp = id & 63;
            float t_s = (float)(s_base + s0 + t2) * (1.0f / 2047.0f);
#pragma unroll
            for (int u2 = 0; u2 < 2; u2++) {
                int mpp = mp + u2;
                float proj = 0.f;
#pragma unroll
                for (int d2 = 0; d2 < 32; d2++) proj = fmaf(kS[t2][d2], omS[d2][mpp], proj);
                float slope = 2.0f - (float)mpp * 0.03125f;
                ktS[t2][mpp]      = cosf(proj) * (INV_SQRT_M * expf(-g * t_s * slope));
                ktS[t2][64 + mpp] = sinf(proj) * (INV_SQRT_M * expf(-g * (1.0f - t_s) * slope));
            }
        }
        __syncthreads();
#pragma unroll
        for (int t2 = 0; t2 < 8; t2++) {
            float vv = vS[t2][e];
#pragma unroll
            for (int i = 0; i < 16; i++) accv[i] = fmaf(ktS[t2][mb + i], vv, accv[i]);
        }
    }
    float* kvp = kvpart + (((size_t)((b * 8 + h) * 4 + sc)) * 128 + mb) * 32 + e;
#pragma unroll
    for (int i = 0; i < 16; i++) kvp[i * 32] = accv[i];
}

// ---------------- fused Q projection + fourier + o = qt @ kv ----------------
// block per (b, h, st); st = quarter of the sequence
__global__ __launch_bounds__(256) void phi_o_fused(
    const float* __restrict__ hc, const float* __restrict__ mean,
    const float* __restrict__ Wq_l, const float* __restrict__ bq_l,
    const float* __restrict__ om_l, const float* __restrict__ g_l,
    const float* __restrict__ kvpart, float* __restrict__ o)
{
    int bx = blockIdx.x;
    int st = bx & 3;
    int h = (bx >> 2) & 7;
    int b = bx >> 5;
    int tid = threadIdx.x;
    __shared__ float WqS[256][32];
    __shared__ float omS[32][64];
    __shared__ float kvS[128][32];
    __shared__ float hcS[8][256];
    __shared__ float qS[8][32];
    __shared__ float qtS[8][128];
    {
        const float* wqp = Wq_l + (size_t)tid * 256 + h * 32;
#pragma unroll
        for (int e4 = 0; e4 < 32; e4 += 4)
            *(float4*)&WqS[tid][e4] = *(const float4*)(wqp + e4);
    }
    for (int i = tid; i < 2048; i += 256) omS[i >> 6][i & 63] = om_l[(size_t)h * 2048 + i];
    {   // sum the 4 kv partials
        const float* p = kvpart + (size_t)(b * 8 + h) * 4 * 4096;
        for (int i = tid; i < 4096; i += 256)
            kvS[i >> 5][i & 31] = p[i] + p[4096 + i] + p[8192 + i] + p[12288 + i];
    }
    float g = g_l[h];
    int e = tid & 31;
    int tsx = tid >> 5;
    float bqe = bq_l[h * 32 + e];
    int s_base = st * 512;
    for (int s0 = 0; s0 < 512; s0 += 8) {
        __syncthreads();
        {
            int row = b * SEQ + s_base + s0 + tsx;
            float mu = mean[row];
            int dc = e * 8;
            const float* hp = hc + (size_t)row * 256 + dc;
            float4 a0 = *(const float4*)hp;
            float4 a1 = *(const float4*)(hp + 4);
            hcS[tsx][dc + 0] = a0.x - mu; hcS[tsx][dc + 1] = a0.y - mu;
            hcS[tsx][dc + 2] = a0.z - mu; hcS[tsx][dc + 3] = a0.w - mu;
            hcS[tsx][dc + 4] = a1.x - mu; hcS[tsx][dc + 5] = a1.y - mu;
            hcS[tsx][dc + 6] = a1.z - mu; hcS[tsx][dc + 7] = a1.w - mu;
        }
        __syncthreads();
        {
            float qa = bqe;
            for (int d = 0; d < 256; d++) qa = fmaf(hcS[tsx][d], WqS[d][e], qa);
            qS[tsx][e] = qa;
        }
        __syncthreads();
        {
            int id = tid * 2;
            int t2 = id >> 6;
            int mp = id & 63;
            float t_s = (float)(s_base + s0 + t2) * (1.0f / 2047.0f);
#pragma unroll
            for (int u2 = 0; u2 < 2; u2++) {
                int mpp = mp + u2;
                float proj = 0.f;
#pragma unroll
                for (int d2 = 0; d2 < 32; d2++) proj = fmaf(qS[t2][d2], omS[d2][mpp], proj);
                float slope = 2.0f - (float)mpp * 0.03125f;
                qtS[t2][mpp]      = cosf(proj) * (INV_SQRT_M * expf(g * t_s * slope));
                qtS[t2][64 + mpp] = sinf(proj) * (INV_SQRT_M * expf(g * (1.0f - t_s) * slope));
            }
        }
        __syncthreads();
        {
            float ov = 0.f;
#pragma unroll
            for (int m = 0; m < 128; m++) ov = fmaf(qtS[tsx][m], kvS[m][e], ov);
            o[((size_t)(b * SEQ + s_base + s0 + tsx)) * 256 + h * 32 + e] = ov;
        }
    }
}

// ---------------- fused FF: out = hc + relu(lc(hc)@W1 + b1)@W2 + b2 ----------------
// block per 64-token tile; Dff processed in chunks of 32
__global__ __launch_bounds__(256) void ff_fused(
    const float* __restrict__ hc, const float* __restrict__ mean,
    const float* __restrict__ W1, const float* __restrict__ b1,
    const float* __restrict__ W2, const float* __restrict__ b2,
    float* __restrict__ out)
{
    int m0 = blockIdx.x * 64;
    int tid = threadIdx.x;
    __shared__ float AS[64][257];
    __shared__ float W1S[256][36];
    __shared__ float W2S[32][260];
    __shared__ float uS[64][33];
    // load centered A tile
    for (int i = tid; i < 64 * 64; i += 256) {
        int off = i * 4;
        int r = off >> 8, c = off & 255;
        int row = m0 + r;
        float mu = mean[row];
        float4 a = *(const float4*)(hc + (size_t)row * 256 + c);
        AS[r][c + 0] = a.x - mu; AS[r][c + 1] = a.y - mu;
        AS[r][c + 2] = a.z - mu; AS[r][c + 3] = a.w - mu;
    }
    int tx = tid & 15;      // output col = jj*16 + tx
    int ty = tid >> 4;      // output rows = ty*4 + i
    float acc[4][16];
#pragma unroll
    for (int i = 0; i < 4; i++) {
        int row = m0 + ty * 4 + i;
#pragma unroll
        for (int jj = 0; jj < 16; jj++) {
            int c = jj * 16 + tx;
            acc[i][jj] = hc[(size_t)row * 256 + c] + b2[c];
        }
    }
    int ur = tid & 63, jg = tid >> 6;   // u-phase: row ur, ff-cols jg*8..jg*8+7
    __syncthreads();
    for (int f0 = 0; f0 < DFF; f0 += 32) {
        {   // load W1 chunk [256 x 32]
            const float* wp = W1 + (size_t)tid * DFF + f0;
#pragma unroll
            for (int j = 0; j < 32; j += 4)
                *(float4*)&W1S[tid][j] = *(const float4*)(wp + j);
        }
        {   // load W2 chunk [32 x 256]
            int j = tid >> 3, c0 = (tid & 7) * 32;
            const float* wp = W2 + (size_t)(f0 + j) * 256 + c0;
#pragma unroll
            for (int c = 0; c < 32; c += 4)
                *(float4*)&W2S[j][c0 + c] = *(const float4*)(wp + c);
        }
        __syncthreads();
        {   // u-phase: u[ur][jg*8+jj] = relu(A[ur,:] @ W1S[:,jg*8+jj] + b1)
            float ua[8];
#pragma unroll
            for (int jj = 0; jj < 8; jj++) ua[jj] = b1[f0 + jg * 8 + jj];
            for (int d = 0; d < 256; d++) {
                float av = AS[ur][d];
                float4 w0 = *(const float4*)&W1S[d][jg * 8];
                float4 w1 = *(const float4*)&W1S[d][jg * 8 + 4];
                ua[0] = fmaf(av, w0.x, ua[0]); ua[1] = fmaf(av, w0.y, ua[1]);
                ua[2] = fmaf(av, w0.z, ua[2]); ua[3] = fmaf(av, w0.w, ua[3]);
                ua[4] = fmaf(av, w1.x, ua[4]); ua[5] = fmaf(av, w1.y, ua[5]);
                ua[6] = fmaf(av, w1.z, ua[6]); ua[7] = fmaf(av, w1.w, ua[7]);
            }
#pragma unroll
            for (int jj = 0; jj < 8; jj++) uS[ur][jg * 8 + jj] = fmaxf(ua[jj], 0.f);
        }
        __syncthreads();
        // acc-phase: acc += u_chunk @ W2_chunk
#pragma unroll 4
        for (int j = 0; j < 32; j++) {
            float us[4];
#pragma unroll
            for (int i = 0; i < 4; i++) us[i] = uS[ty * 4 + i][j];
#pragma unroll
            for (int jj = 0; jj < 16; jj++) {
                float wv = W2S[j][jj * 16 + tx];
#pragma unroll
                for (int i = 0; i < 4; i++) acc[i][jj] = fmaf(us[i], wv, acc[i][jj]);
            }
        }
        __syncthreads();
    }
#pragma unroll
    for (int i = 0; i < 4; i++) {
        int row = m0 + ty * 4 + i;
#pragma unroll
        for (int jj = 0; jj < 16; jj++)
            out[(size_t)row * 256 + jj * 16 + tx] = acc[i][jj];
    }
}

// ---------------- host ----------------

extern "C" void kernel_launch(void* const* d_in, const int* in_sizes, int n_in,
                              void* d_out, int out_size, void* d_ws, size_t ws_size,
                              hipStream_t stream)
{
    (void)in_sizes; (void)n_in; (void)out_size; (void)ws_size;
    const float* x    = (const float*)d_in[0];
    const float* cw0  = (const float*)d_in[1];
    const float* cb0  = (const float*)d_in[2];
    const float* cw1  = (const float*)d_in[3];
    const float* cb1  = (const float*)d_in[4];
    const float* cw2  = (const float*)d_in[5];
    const float* cb2  = (const float*)d_in[6];
    const float* Wq   = (const float*)d_in[7];
    const float* bq   = (const float*)d_in[8];
    const float* Wk   = (const float*)d_in[9];
    const float* bk   = (const float*)d_in[10];
    const float* Wv   = (const float*)d_in[11];
    const float* bv   = (const float*)d_in[12];
    const float* Wo   = (const float*)d_in[13];
    const float* bo   = (const float*)d_in[14];
    const float* omega= (const float*)d_in[15];
    const float* gamma= (const float*)d_in[16];
    const float* W1   = (const float*)d_in[17];
    const float* b1   = (const float*)d_in[18];
    const float* W2   = (const float*)d_in[19];
    const float* b2   = (const float*)d_in[20];

    // ws layout (floats): hc [16 MB] | meanb [64 KB] | kvpart [4 MB]  => ~20.1 MB total
    float* ws    = (float*)d_ws;
    float* hc    = ws;
    float* meanb = hc + (size_t)BS_TOK * DMODEL;            // +4,194,304
    float* kvpart= meanb + BS_TOK;                          // +16,384
    // d_out doubles as scratch: conv stem temporaries, then o
    float* h0 = (float*)d_out;                              // B*L1P*8  = 2,097,152 floats
    float* h1 = (float*)d_out + (size_t)BATCH * L1P * 8;    // B*L2P*16 = 1,048,576 floats
    float* o  = (float*)d_out;                              // BS_TOK*256 floats

    conv0_kernel<<<(BATCH * L1P + 255) / 256, 256, 0, stream>>>(x, cw0, cb0, h0);
    conv1_kernel<<<(BATCH * L2P + 255) / 256, 256, 0, stream>>>(h0, cw1, cb1, h1);
    conv2_kernel<<<BATCH * SEQ, 256, 0, stream>>>(h1, cw2, cb2, hc);

    for (int l = 0; l < 2; l++) {
        const float* Wq_l = Wq + (size_t)l * DMODEL * DMODEL;
        const float* bq_l = bq + (size_t)l * DMODEL;
        const float* Wk_l = Wk + (size_t)l * DMODEL * DMODEL;
        const float* bk_l = bk + (size_t)l * DMODEL;
        const float* Wv_l = Wv + (size_t)l * DMODEL * DMODEL;
        const float* bv_l = bv + (size_t)l * DMODEL;
        const float* Wo_l = Wo + (size_t)l * DMODEL * DMODEL;
        const float* bo_l = bo + (size_t)l * DMODEL;
        const float* om_l = omega + (size_t)l * NHEAD * DHEAD * MHALF;
        const float* g_l  = gamma + (size_t)l * NHEAD;
        const float* W1_l = W1 + (size_t)l * DMODEL * DFF;
        const float* b1_l = b1 + (size_t)l * DFF;
        const float* W2_l = W2 + (size_t)l * DFF * DMODEL;
        const float* b2_l = b2 + (size_t)l * DMODEL;

        rowmean_kernel<<<BS_TOK, 64, 0, stream>>>(hc, meanb);
        phi_kv_fused<<<BATCH * NHEAD * 4, 256, 0, stream>>>(
            hc, meanb, Wk_l, bk_l, Wv_l, bv_l, om_l, g_l, kvpart);
        phi_o_fused<<<BATCH * NHEAD * 4, 256, 0, stream>>>(
            hc, meanb, Wq_l, bq_l, om_l, g_l, kvpart, o);
        gemm_kernel<false, false, true><<<dim3(DMODEL / 64, BS_TOK / 64), 256, 0, stream>>>(
            o, Wo_l, bo_l, nullptr, hc, hc, BS_TOK, DMODEL, DMODEL);

        rowmean_kernel<<<BS_TOK, 64, 0, stream>>>(hc, meanb);
        float* outC = (l == 1) ? (float*)d_out : hc;
        ff_fused<<<BS_TOK / 64, 256, 0, stream>>>(
            hc, meanb, W1_l, b1_l, W2_l, b2_l, outC);
    }
}